// Round 3
// baseline (1208.322 us; speedup 1.0000x reference)
//
#include <hip/hip_runtime.h>
#include <hip/hip_bf16.h>

#define DD 51
#define DM 50
#define BB 8192
#define MM (DD*DD)   // 2601
#define NBUCKET 256

__device__ __forceinline__ float wave_sum(float v) {
    #pragma unroll
    for (int off = 32; off; off >>= 1) v += __shfl_xor(v, off);
    return v;
}

// ---------------- zero the accumulator buckets (graph-safe, pure kernel) ----
__global__ __launch_bounds__(256) void zero_kernel(float* __restrict__ buckets) {
    buckets[threadIdx.x] = 0.f;
}

// ---------------- matvec losses: nf1 / nf3 / nf4 / nf3_neg ----------------
// one 64-thread block per (type, b). The 51x51 rel matrix is staged into LDS
// with coalesced global loads; lane i then computes row i of both matvecs
// from LDS (row stride 51 = odd -> worst 2-way bank aliasing, free).
__global__ __launch_bounds__(64) void matvec_loss_kernel(
    const int* __restrict__ nf1, const int* __restrict__ nf3,
    const int* __restrict__ nf4, const int* __restrict__ nfneg,
    const float* __restrict__ cls,
    const float* __restrict__ rel,
    float* __restrict__ buckets)
{
    int task = blockIdx.x;
    int type = task >> 13;          // 8192 = 2^13
    int b    = task & (BB - 1);
    int ci, ri, di;
    if (type == 0)      { ci = nf1[3*b];   ri = nf1[3*b+1];   di = nf1[3*b+2]; }
    else if (type == 1) { ci = nf3[3*b];   ri = nf3[3*b+1];   di = nf3[3*b+2]; }
    else if (type == 2) { ri = nf4[3*b];   ci = nf4[3*b+1];   di = nf4[3*b+2]; }
    else                { ci = nfneg[3*b]; ri = nfneg[3*b+1]; di = nfneg[3*b+2]; }

    __shared__ float M[MM];
    __shared__ float sc[DD], sd[DD];
    int lane = threadIdx.x;

    const float* Mg = rel + (size_t)ri * MM;
    for (int p = lane; p < MM; p += 64) M[p] = Mg[p];

    float cv = 0.f, dv = 0.f;
    if (lane < DD) {
        cv = cls[(size_t)ci * DD + lane];
        dv = cls[(size_t)di * DD + lane];
        sc[lane] = cv; sd[lane] = dv;
    }
    __syncthreads();

    float cr = 0.f, dr = 0.f;
    if (lane < DD) {
        const float* row = &M[lane * DD];
        #pragma unroll
        for (int j = 0; j < DD; ++j) {
            float m = row[j];
            cr = fmaf(m, sc[j], cr);
            dr = fmaf(m, sd[j], dr);
        }
    }
    float t  = (lane < DM) ? (dr - cr) : 0.f;
    float e2 = t * t;
    float c2 = (lane < DM) ? cv * cv : 0.f;
    float d2 = (lane < DM) ? dv * dv : 0.f;
    e2 = wave_sum(e2); c2 = wave_sum(c2); d2 = wave_sum(d2);

    float cr50 = __shfl(cr, DM);
    float dr50 = __shfl(dr, DM);
    float c50  = __shfl(cv, DM);
    float d50  = __shfl(dv, DM);

    if (lane == 0) {
        float euc = sqrtf(e2);
        float reg = fabsf(sqrtf(c2) - 1.f) + fabsf(sqrtf(d2) - 1.f);
        float L;
        if (type == 0) {
            float rc = fmaxf(cr50, 0.f), rd = fmaxf(dr50, 0.f);
            L = fmaxf(euc + rc - rd, 0.f) + reg;           // nf1
        } else if (type == 1) {
            float rc = fmaxf(c50, 0.f), rd = fmaxf(d50, 0.f);
            L = fmaxf(euc + rc - rd, 0.f) + reg;           // nf3
        } else if (type == 2) {
            float rc = fmaxf(c50, 0.f), rd = fmaxf(d50, 0.f);
            L = fmaxf(euc - (rc + rd), 0.f) + reg;         // nf4
        } else {
            float rc = fmaxf(c50, 0.f), rd = fmaxf(d50, 0.f);
            L = -(euc - rc - rd) + reg;                    // nf3_neg
        }
        atomicAdd(&buckets[task & (NBUCKET - 1)], L);
    }
}

// ---------------- chain loss: mean |E - C@D| ----------------
// one 256-thread block per b. C stored transposed in LDS, rows padded to 52
// (16B-aligned float4). Thread t<169 computes a 4x4 output tile.
__global__ __launch_bounds__(256) void chain_kernel(
    const int* __restrict__ nfc,
    const float* __restrict__ rel,
    float* __restrict__ buckets)
{
    int b  = blockIdx.x;
    int ic = nfc[3*b], id = nfc[3*b+1], ie = nfc[3*b+2];
    alignas(16) __shared__ float CsT[DD][52];  // CsT[k][i] = C[i][k]
    alignas(16) __shared__ float Ds [DD][52];  // Ds[k][j]  = D[k][j]
    const float* Cg = rel + (size_t)ic * MM;
    const float* Dg = rel + (size_t)id * MM;
    const float* Eg = rel + (size_t)ie * MM;

    int t = threadIdx.x;
    for (int p = t; p < MM; p += 256) {
        int i = p / DD, j = p - i * DD;
        CsT[j][i] = Cg[p];
        Ds [i][j] = Dg[p];
    }
    __syncthreads();

    float local = 0.f;
    if (t < 169) {
        int ti = t / 13, tj = t - ti * 13;
        int i0 = ti * 4, j0 = tj * 4;
        float acc[4][4];
        #pragma unroll
        for (int r = 0; r < 4; ++r)
            #pragma unroll
            for (int c = 0; c < 4; ++c) acc[r][c] = 0.f;

        for (int k = 0; k < DD; ++k) {
            float4 ca = *(const float4*)&CsT[k][i0];
            float4 db = *(const float4*)&Ds [k][j0];
            float a[4]  = {ca.x, ca.y, ca.z, ca.w};
            float bv[4] = {db.x, db.y, db.z, db.w};
            #pragma unroll
            for (int r = 0; r < 4; ++r)
                #pragma unroll
                for (int c = 0; c < 4; ++c)
                    acc[r][c] = fmaf(a[r], bv[c], acc[r][c]);
        }
        #pragma unroll
        for (int r = 0; r < 4; ++r) {
            int i = i0 + r;
            if (i < DD) {
                #pragma unroll
                for (int c = 0; c < 4; ++c) {
                    int j = j0 + c;
                    if (j < DD)
                        local += fabsf(Eg[i * DD + j] - acc[r][c]);
                }
            }
        }
    }
    local = wave_sum(local);
    __shared__ float wsum[4];
    if ((t & 63) == 0) wsum[t >> 6] = local;
    __syncthreads();
    if (t == 0) {
        float s = (wsum[0] + wsum[1] + wsum[2] + wsum[3]) * (1.f / (float)MM);
        atomicAdd(&buckets[b & (NBUCKET - 1)], s);
    }
}

// ---------------- nf2 + top + radius ----------------
__global__ __launch_bounds__(64) void misc_kernel(
    const int* __restrict__ nf2, const int* __restrict__ top,
    const int* __restrict__ radius,
    const float* __restrict__ cls,
    float* __restrict__ buckets)
{
    int b = blockIdx.x;
    int i0 = nf2[3*b], i1 = nf2[3*b+1], i2 = nf2[3*b+2];
    int lane = threadIdx.x;
    float cv = 0.f, dv = 0.f, ev = 0.f;
    if (lane < DD) {
        cv = cls[(size_t)i0 * DD + lane];
        dv = cls[(size_t)i1 * DD + lane];
        ev = cls[(size_t)i2 * DD + lane];
    }
    float m = (lane < DM) ? 1.f : 0.f;
    float s_dc = (dv - cv) * (dv - cv) * m;
    float s_ec = (ev - cv) * (ev - cv) * m;
    float s_ed = (ev - dv) * (ev - dv) * m;
    float s_c  = cv * cv * m;
    float s_d  = dv * dv * m;
    float s_e  = ev * ev * m;
    s_dc = wave_sum(s_dc); s_ec = wave_sum(s_ec); s_ed = wave_sum(s_ed);
    s_c  = wave_sum(s_c);  s_d  = wave_sum(s_d);  s_e  = wave_sum(s_e);

    float c50 = __shfl(cv, DM), d50 = __shfl(dv, DM), e50 = __shfl(ev, DM);
    if (lane == 0) {
        float rc = fmaxf(c50, 0.f), rd = fmaxf(d50, 0.f), re = fmaxf(e50, 0.f);
        float L = fmaxf(sqrtf(s_dc) - (rc + rd), 0.f)
                + fmaxf(sqrtf(s_ec) - rc, 0.f)
                + fmaxf(sqrtf(s_ed) - rd, 0.f)
                + fmaxf(fminf(rc, rd) - re, 0.f)
                + fabsf(sqrtf(s_c) - 1.f)
                + fabsf(sqrtf(s_d) - 1.f)
                + fabsf(sqrtf(s_e) - 1.f);
        // top loss: |relu(cls[top[b]][-1]) - 5|
        float t50 = cls[(size_t)top[b] * DD + DM];
        L += fabsf(fmaxf(t50, 0.f) - 5.f);
        // -radius loss: -min(0, cls[radius[b]][-1])
        float r50 = cls[(size_t)radius[b] * DD + DM];
        L -= fminf(r50, 0.f);
        atomicAdd(&buckets[b & (NBUCKET - 1)], L);
    }
}

// ---------------- finalize: mean over B, float32 scalar ----------------
__global__ __launch_bounds__(64) void finalize_kernel(
    const float* __restrict__ buckets, float* __restrict__ out)
{
    int t = threadIdx.x;
    float v = buckets[t] + buckets[t + 64] + buckets[t + 128] + buckets[t + 192];
    v = wave_sum(v);
    if (t == 0) out[0] = v * (1.f / (float)BB);
}

extern "C" void kernel_launch(void* const* d_in, const int* in_sizes, int n_in,
                              void* d_out, int out_size, void* d_ws, size_t ws_size,
                              hipStream_t stream) {
    const int* nf1     = (const int*)d_in[0];
    const int* nf2     = (const int*)d_in[1];
    const int* nf3     = (const int*)d_in[2];
    const int* nf4     = (const int*)d_in[3];
    const int* top     = (const int*)d_in[4];
    const int* nf3n    = (const int*)d_in[5];
    // d_in[6] = nf_inclusion (unused by reference)
    const int* nfc     = (const int*)d_in[7];
    const int* radius  = (const int*)d_in[8];
    const float* cls   = (const float*)d_in[9];
    const float* rel   = (const float*)d_in[10];

    float* buckets = (float*)d_ws;

    zero_kernel<<<1, NBUCKET, 0, stream>>>(buckets);
    matvec_loss_kernel<<<4 * BB, 64, 0, stream>>>(nf1, nf3, nf4, nf3n, cls, rel, buckets);
    chain_kernel<<<BB, 256, 0, stream>>>(nfc, rel, buckets);
    misc_kernel<<<BB, 64, 0, stream>>>(nf2, top, radius, cls, buckets);
    finalize_kernel<<<1, 64, 0, stream>>>(buckets, (float*)d_out);
}

// Round 4
// 737.596 us; speedup vs baseline: 1.6382x; 1.6382x over previous
//
#include <hip/hip_runtime.h>
#include <hip/hip_bf16.h>

#define DD 51
#define DM 50
#define BB 8192
#define MM (DD*DD)   // 2601
#define NBUCKET 1024

__device__ __forceinline__ float wave_sum(float v) {
    #pragma unroll
    for (int off = 32; off; off >>= 1) v += __shfl_xor(v, off);
    return v;
}

// ---------------- zero the accumulator buckets (graph-safe, pure kernel) ----
__global__ __launch_bounds__(256) void zero_kernel(float* __restrict__ buckets) {
    buckets[blockIdx.x * 256 + threadIdx.x] = 0.f;
}

// ---------------- matvec losses: nf1 / nf3 / nf4 / nf3_neg ----------------
// one 128-thread (2-wave) block per (type, b). Both waves cooperatively stage
// the 51x51 rel matrix into LDS (coalesced); wave0 computes cr = M@c, wave1
// computes dr = M@d (lane = row). Results exchanged via LDS; wave0 does the
// epilogue. 11.2 KB LDS -> 14 blocks = 28 waves/CU.
__global__ __launch_bounds__(128, 8) void matvec_loss_kernel(
    const int* __restrict__ nf1, const int* __restrict__ nf3,
    const int* __restrict__ nf4, const int* __restrict__ nfneg,
    const float* __restrict__ cls,
    const float* __restrict__ rel,
    float* __restrict__ buckets)
{
    int task = blockIdx.x;
    int type = task >> 13;          // 8192 = 2^13
    int b    = task & (BB - 1);
    int ci, ri, di;
    if (type == 0)      { ci = nf1[3*b];   ri = nf1[3*b+1];   di = nf1[3*b+2]; }
    else if (type == 1) { ci = nf3[3*b];   ri = nf3[3*b+1];   di = nf3[3*b+2]; }
    else if (type == 2) { ri = nf4[3*b];   ci = nf4[3*b+1];   di = nf4[3*b+2]; }
    else                { ci = nfneg[3*b]; ri = nfneg[3*b+1]; di = nfneg[3*b+2]; }

    __shared__ float M[MM];
    __shared__ float sc[DD], sd[DD], scr[DD], sdr[DD];
    int tid  = threadIdx.x;
    int wave = tid >> 6;
    int lane = tid & 63;

    const float* Mg = rel + (size_t)ri * MM;
    #pragma unroll 4
    for (int p = tid; p < MM; p += 128) M[p] = Mg[p];   // 21 coalesced iters

    if (wave == 0) { if (lane < DD) sc[lane] = cls[(size_t)ci * DD + lane]; }
    else           { if (lane < DD) sd[lane] = cls[(size_t)di * DD + lane]; }
    __syncthreads();

    const float* vec = wave ? sd : sc;
    float acc = 0.f;
    if (lane < DD) {
        const float* row = &M[lane * DD];
        #pragma unroll
        for (int j = 0; j < DD; ++j) acc = fmaf(row[j], vec[j], acc);
        if (wave == 0) scr[lane] = acc; else sdr[lane] = acc;
    }
    __syncthreads();

    if (wave == 0) {
        float cv  = (lane < DM) ? sc[lane]  : 0.f;
        float dv  = (lane < DM) ? sd[lane]  : 0.f;
        float crv = (lane < DM) ? scr[lane] : 0.f;
        float drv = (lane < DM) ? sdr[lane] : 0.f;
        float t  = drv - crv;
        float e2 = wave_sum(t * t);
        float c2 = wave_sum(cv * cv);
        float d2 = wave_sum(dv * dv);
        if (lane == 0) {
            float euc = sqrtf(e2);
            float reg = fabsf(sqrtf(c2) - 1.f) + fabsf(sqrtf(d2) - 1.f);
            float L;
            if (type == 0) {
                float rc = fmaxf(scr[DM], 0.f), rd = fmaxf(sdr[DM], 0.f);
                L = fmaxf(euc + rc - rd, 0.f) + reg;           // nf1
            } else if (type == 1) {
                float rc = fmaxf(sc[DM], 0.f), rd = fmaxf(sd[DM], 0.f);
                L = fmaxf(euc + rc - rd, 0.f) + reg;           // nf3
            } else if (type == 2) {
                float rc = fmaxf(sc[DM], 0.f), rd = fmaxf(sd[DM], 0.f);
                L = fmaxf(euc - (rc + rd), 0.f) + reg;         // nf4
            } else {
                float rc = fmaxf(sc[DM], 0.f), rd = fmaxf(sd[DM], 0.f);
                L = -(euc - rc - rd) + reg;                    // nf3_neg
            }
            atomicAdd(&buckets[task & (NBUCKET - 1)], L);
        }
    }
}

// ---------------- chain loss: mean |E - C@D| ----------------
// one 256-thread block per b. C stored transposed in LDS, rows padded to 52
// (16B-aligned float4). Thread t<169 computes a 4x4 output tile.
// launch_bounds(256,4): cap VGPR at 128 -> 4 blocks/CU (was 256 VGPR, 11% occ).
__global__ __launch_bounds__(256, 4) void chain_kernel(
    const int* __restrict__ nfc,
    const float* __restrict__ rel,
    float* __restrict__ buckets)
{
    int b  = blockIdx.x;
    int ic = nfc[3*b], id = nfc[3*b+1], ie = nfc[3*b+2];
    alignas(16) __shared__ float CsT[DD][52];  // CsT[k][i] = C[i][k]
    alignas(16) __shared__ float Ds [DD][52];  // Ds[k][j]  = D[k][j]
    const float* Cg = rel + (size_t)ic * MM;
    const float* Dg = rel + (size_t)id * MM;
    const float* Eg = rel + (size_t)ie * MM;

    int t = threadIdx.x;
    for (int p = t; p < MM; p += 256) {
        int i = p / DD, j = p - i * DD;
        CsT[j][i] = Cg[p];
        Ds [i][j] = Dg[p];
    }
    __syncthreads();

    float local = 0.f;
    if (t < 169) {
        int ti = t / 13, tj = t - ti * 13;
        int i0 = ti * 4, j0 = tj * 4;
        float acc[4][4];
        #pragma unroll
        for (int r = 0; r < 4; ++r)
            #pragma unroll
            for (int c = 0; c < 4; ++c) acc[r][c] = 0.f;

        #pragma unroll 3
        for (int k = 0; k < DD; ++k) {
            float4 ca = *(const float4*)&CsT[k][i0];
            float4 db = *(const float4*)&Ds [k][j0];
            float a[4]  = {ca.x, ca.y, ca.z, ca.w};
            float bv[4] = {db.x, db.y, db.z, db.w};
            #pragma unroll
            for (int r = 0; r < 4; ++r)
                #pragma unroll
                for (int c = 0; c < 4; ++c)
                    acc[r][c] = fmaf(a[r], bv[c], acc[r][c]);
        }
        #pragma unroll
        for (int r = 0; r < 4; ++r) {
            int i = i0 + r;
            if (i < DD) {
                #pragma unroll
                for (int c = 0; c < 4; ++c) {
                    int j = j0 + c;
                    if (j < DD)
                        local += fabsf(Eg[i * DD + j] - acc[r][c]);
                }
            }
        }
    }
    local = wave_sum(local);
    __shared__ float wsum[4];
    if ((t & 63) == 0) wsum[t >> 6] = local;
    __syncthreads();
    if (t == 0) {
        float s = (wsum[0] + wsum[1] + wsum[2] + wsum[3]) * (1.f / (float)MM);
        atomicAdd(&buckets[b & (NBUCKET - 1)], s);
    }
}

// ---------------- nf2 + top + radius ----------------
__global__ __launch_bounds__(64) void misc_kernel(
    const int* __restrict__ nf2, const int* __restrict__ top,
    const int* __restrict__ radius,
    const float* __restrict__ cls,
    float* __restrict__ buckets)
{
    int b = blockIdx.x;
    int i0 = nf2[3*b], i1 = nf2[3*b+1], i2 = nf2[3*b+2];
    int lane = threadIdx.x;
    float cv = 0.f, dv = 0.f, ev = 0.f;
    if (lane < DD) {
        cv = cls[(size_t)i0 * DD + lane];
        dv = cls[(size_t)i1 * DD + lane];
        ev = cls[(size_t)i2 * DD + lane];
    }
    float m = (lane < DM) ? 1.f : 0.f;
    float s_dc = wave_sum((dv - cv) * (dv - cv) * m);
    float s_ec = wave_sum((ev - cv) * (ev - cv) * m);
    float s_ed = wave_sum((ev - dv) * (ev - dv) * m);
    float s_c  = wave_sum(cv * cv * m);
    float s_d  = wave_sum(dv * dv * m);
    float s_e  = wave_sum(ev * ev * m);

    float c50 = __shfl(cv, DM), d50 = __shfl(dv, DM), e50 = __shfl(ev, DM);
    if (lane == 0) {
        float rc = fmaxf(c50, 0.f), rd = fmaxf(d50, 0.f), re = fmaxf(e50, 0.f);
        float L = fmaxf(sqrtf(s_dc) - (rc + rd), 0.f)
                + fmaxf(sqrtf(s_ec) - rc, 0.f)
                + fmaxf(sqrtf(s_ed) - rd, 0.f)
                + fmaxf(fminf(rc, rd) - re, 0.f)
                + fabsf(sqrtf(s_c) - 1.f)
                + fabsf(sqrtf(s_d) - 1.f)
                + fabsf(sqrtf(s_e) - 1.f);
        float t50 = cls[(size_t)top[b] * DD + DM];
        L += fabsf(fmaxf(t50, 0.f) - 5.f);
        float r50 = cls[(size_t)radius[b] * DD + DM];
        L -= fminf(r50, 0.f);
        atomicAdd(&buckets[b & (NBUCKET - 1)], L);
    }
}

// ---------------- finalize: mean over B, float32 scalar ----------------
__global__ __launch_bounds__(256) void finalize_kernel(
    const float* __restrict__ buckets, float* __restrict__ out)
{
    int t = threadIdx.x;
    float v = buckets[t] + buckets[t + 256] + buckets[t + 512] + buckets[t + 768];
    v = wave_sum(v);
    __shared__ float ws[4];
    if ((t & 63) == 0) ws[t >> 6] = v;
    __syncthreads();
    if (t == 0) out[0] = (ws[0] + ws[1] + ws[2] + ws[3]) * (1.f / (float)BB);
}

extern "C" void kernel_launch(void* const* d_in, const int* in_sizes, int n_in,
                              void* d_out, int out_size, void* d_ws, size_t ws_size,
                              hipStream_t stream) {
    const int* nf1     = (const int*)d_in[0];
    const int* nf2     = (const int*)d_in[1];
    const int* nf3     = (const int*)d_in[2];
    const int* nf4     = (const int*)d_in[3];
    const int* top     = (const int*)d_in[4];
    const int* nf3n    = (const int*)d_in[5];
    // d_in[6] = nf_inclusion (unused by reference)
    const int* nfc     = (const int*)d_in[7];
    const int* radius  = (const int*)d_in[8];
    const float* cls   = (const float*)d_in[9];
    const float* rel   = (const float*)d_in[10];

    float* buckets = (float*)d_ws;

    zero_kernel<<<NBUCKET / 256, 256, 0, stream>>>(buckets);
    matvec_loss_kernel<<<4 * BB, 128, 0, stream>>>(nf1, nf3, nf4, nf3n, cls, rel, buckets);
    chain_kernel<<<BB, 256, 0, stream>>>(nfc, rel, buckets);
    misc_kernel<<<BB, 64, 0, stream>>>(nf2, top, radius, cls, buckets);
    finalize_kernel<<<1, 256, 0, stream>>>(buckets, (float*)d_out);
}